// Round 5
// baseline (113.549 us; speedup 1.0000x reference)
//
#include <hip/hip_runtime.h>
#include <math.h>

#define NB 2
#define SS 256
#define DD 768
#define NH 12
#define WW 64

using f32x4  = __attribute__((ext_vector_type(4))) float;
using bf16x8 = __attribute__((ext_vector_type(8))) short;

constexpr float R2  = 0.25f;           // R/2: revolutions pre-scale for v_sin/v_cos
constexpr float C8  = 4.1168160e-7f;   // (2*pi)^-8
constexpr float EPS = 1e-4f;

// ws layout (bytes):
//   qkv f32:  [0, 4718592)         3 * (2*12*256*64) * 4
//   A' bf16:  [4718592, 6291456)   512 x 1536  (xh | xl)
//   B' bf16:  [6291456, 13369344)  2304 x 1536 (Wh | Wl)
//   QT  f32:  [13369344, 18087936) [bh][row][3][64]  (q*R2, sin, cos)
//   KT  f32:  [18087936, 22806528) [bh][dim][3][256] (k*R2, sin, cos) key-coalesced
#define QKV_ELEMS (NB*NH*SS*WW)
#define A_OFF_BYTES  4718592u
#define B_OFF_BYTES  6291456u
#define QT_OFF_BYTES 13369344u
#define KT_OFF_BYTES 18087936u

#define XBLKS 384    // 512*768/4/256
#define WBLKS 1728   // 3*768*768/4/256

__device__ __forceinline__ unsigned short bf16_rn(float f) {
    unsigned u = __builtin_bit_cast(unsigned, f);
    u += 0x7fffu + ((u >> 16) & 1u);
    return (unsigned short)(u >> 16);
}

// ---------------- merged split conversions: x -> A' [xh|xl], W -> B' [Wh|Wl] ----------------
__global__ __launch_bounds__(256) void conv_all(
        const float* __restrict__ x,
        const float* __restrict__ Wq, const float* __restrict__ Wk, const float* __restrict__ Wv,
        unsigned short* __restrict__ A, unsigned short* __restrict__ B) {
    int bid = blockIdx.x;
    const float* src;
    unsigned short* dstrow;
    if (bid < XBLKS) {
        int idx = bid * 256 + threadIdx.x;
        int m = idx / (DD/4);
        int c = (idx - m*(DD/4)) * 4;
        src = x + (size_t)idx * 4;
        dstrow = A + (size_t)m * 1536 + c;
    } else {
        int idx = (bid - XBLKS) * 256 + threadIdx.x;
        int p = idx / (768*192);
        int rem = idx - p*(768*192);
        const float* W = (p == 0) ? Wq : (p == 1) ? Wk : Wv;
        int j = rem / 192;
        int c = (rem - j*192) * 4;
        src = W + (size_t)rem * 4;
        dstrow = B + (size_t)(p*768 + j) * 1536 + c;
    }
    float4 v = *reinterpret_cast<const float4*>(src);
    float vv[4] = {v.x, v.y, v.z, v.w};
    unsigned short h[4], l[4];
    #pragma unroll
    for (int e = 0; e < 4; ++e) {
        h[e] = bf16_rn(vv[e]);
        float hf = __builtin_bit_cast(float, (unsigned)h[e] << 16);
        l[e] = bf16_rn(vv[e] - hf);
    }
    *reinterpret_cast<ushort4*>(dstrow)       = make_ushort4(h[0], h[1], h[2], h[3]);
    *reinterpret_cast<ushort4*>(dstrow + 768) = make_ushort4(l[0], l[1], l[2], l[3]);
}

// ---------------- split-bf16 MFMA GEMM v2: 64x64 tile, full-K per wave, direct epilogue ----------------
// grid (8, 36); 4 waves in 2x2; each wave a 32x32 quadrant (2x2 16x16 frags), K = 3 segs x 768.
__global__ __launch_bounds__(256) void gemm_qkv(
        const unsigned short* __restrict__ A, const unsigned short* __restrict__ B,
        const float* __restrict__ bq, const float* __restrict__ bk, const float* __restrict__ bv,
        float* __restrict__ qkv) {
    const int tid = threadIdx.x;
    const int wid = tid >> 6, l = tid & 63;
    const int lr = l & 15, lo_ = l >> 4;
    const int m0 = blockIdx.x * 64 + (wid >> 1) * 32;
    const int nb = blockIdx.y;                       // 64-col tile: one head, one of q/k/v
    const int n0 = nb * 64 + (wid & 1) * 32;

    const unsigned short* Ap = A + (size_t)(m0 + lr) * 1536 + lo_ * 8;
    const unsigned short* Bp = B + (size_t)(n0 + lr) * 1536 + lo_ * 8;

    f32x4 acc00 = 0.f, acc01 = 0.f, acc10 = 0.f, acc11 = 0.f;
    #pragma unroll
    for (int seg = 0; seg < 3; ++seg) {
        const unsigned short* As = Ap + ((seg == 2) ? 768 : 0);   // xl for seg2
        const unsigned short* Bs = Bp + ((seg == 1) ? 768 : 0);   // Wl for seg1
        #pragma unroll 6
        for (int k = 0; k < 24; ++k) {
            bf16x8 a0 = *reinterpret_cast<const bf16x8*>(As + k*32);
            bf16x8 a1 = *reinterpret_cast<const bf16x8*>(As + 16*1536 + k*32);
            bf16x8 b0 = *reinterpret_cast<const bf16x8*>(Bs + k*32);
            bf16x8 b1 = *reinterpret_cast<const bf16x8*>(Bs + 16*1536 + k*32);
            acc00 = __builtin_amdgcn_mfma_f32_16x16x32_bf16(a0, b0, acc00, 0, 0, 0);
            acc01 = __builtin_amdgcn_mfma_f32_16x16x32_bf16(a0, b1, acc01, 0, 0, 0);
            acc10 = __builtin_amdgcn_mfma_f32_16x16x32_bf16(a1, b0, acc10, 0, 0, 0);
            acc11 = __builtin_amdgcn_mfma_f32_16x16x32_bf16(a1, b1, acc11, 0, 0, 0);
        }
    }
    // Direct epilogue. D layout: m = (lane>>4)*4 + reg (+fi*16), n = lane&15 (+fj*16).
    const int which = nb / 12;
    const int head  = nb - which * 12;
    const float* bias = (which == 0) ? bq : (which == 1) ? bk : bv;
    float* obase = qkv + (size_t)which * QKV_ELEMS;
    #pragma unroll
    for (int fi = 0; fi < 2; ++fi) {
        #pragma unroll
        for (int fj = 0; fj < 2; ++fj) {
            f32x4 a = (fi == 0) ? ((fj == 0) ? acc00 : acc01)
                                : ((fj == 0) ? acc10 : acc11);
            int w = (wid & 1) * 32 + fj * 16 + lr;
            float bb = bias[head * 64 + w];
            #pragma unroll
            for (int j = 0; j < 4; ++j) {
                int row = m0 + fi * 16 + lo_ * 4 + j;
                int b_ = row >> 8, s_ = row & 255;
                obase[(((size_t)b_ * NH + head) * SS + s_) * WW + w] = a[j] + bb;
            }
        }
    }
}

// ---------------- prep: q,k -> (val*R2, sin, cos) triples ----------------
// grid (4, 24): chunk of 64 keys x bh. wave = 16-dim slice, lane = key.
__global__ __launch_bounds__(256) void prep(const float* __restrict__ qkv,
                                            float* __restrict__ QT, float* __restrict__ KT) {
    const int c = blockIdx.x, bh = blockIdx.y;
    const int lane = threadIdx.x & 63, wv = threadIdx.x >> 6;
    const int key = c * 64 + lane;
    const int d0 = wv * 16;
    const float* q = qkv + ((size_t)bh * SS + key) * WW + d0;
    const float* k = qkv + QKV_ELEMS + ((size_t)bh * SS + key) * WW + d0;
    float* qt = QT + ((size_t)bh * SS + key) * 3 * WW;     // [key][3][64]
    float* kt = KT + (size_t)bh * WW * 3 * SS;             // [d][3][256]
    #pragma unroll
    for (int g = 0; g < 4; ++g) {
        float4 qv = *reinterpret_cast<const float4*>(q + g * 4);
        float4 kv = *reinterpret_cast<const float4*>(k + g * 4);
        float qa[4] = {qv.x, qv.y, qv.z, qv.w};
        float ka[4] = {kv.x, kv.y, kv.z, kv.w};
        f32x4 qr, qs, qc;
        #pragma unroll
        for (int e = 0; e < 4; ++e) {
            float a = R2 * qa[e];
            qr[e] = a;
            qs[e] = __builtin_amdgcn_sinf(a);
            qc[e] = __builtin_amdgcn_cosf(a);
        }
        *reinterpret_cast<f32x4*>(qt + 0 * WW + d0 + g * 4) = qr;
        *reinterpret_cast<f32x4*>(qt + 1 * WW + d0 + g * 4) = qs;
        *reinterpret_cast<f32x4*>(qt + 2 * WW + d0 + g * 4) = qc;
        #pragma unroll
        for (int e = 0; e < 4; ++e) {
            float a = R2 * ka[e];
            int d = d0 + g * 4 + e;
            kt[(d * 3 + 0) * SS + key] = a;
            kt[(d * 3 + 1) * SS + key] = __builtin_amdgcn_sinf(a);
            kt[(d * 3 + 2) * SS + key] = __builtin_amdgcn_cosf(a);
        }
    }
}

// ---------------- Fourier attention v5: transcendental-free inner loop ----------------
// thread = key. Per 8-dim group: k-triple in regs (coalesced loads from KT),
// q-triple broadcast from LDS. Eval: sin(q^-k^) = sq*ck - cq*sk -> 8 full-rate VALU,
// 0 trans ops. |t|<EPS -> factor 1 via cndmask. One rcp per 8 dims. Scores <= 1.
__global__ __launch_bounds__(256, 3) void fattn(
    const float* __restrict__ qkv, const float* __restrict__ QT, const float* __restrict__ KT,
    const float* __restrict__ mask, float* __restrict__ out)
{
    const int bh = blockIdx.y;
    const int b = bh / NH, h = bh - b * NH;
    const int row0 = blockIdx.x * 8;

    const float* Vg = qkv + (size_t)(2 * QKV_ELEMS) + (size_t)bh * SS * WW;
    const float* kt = KT + (size_t)bh * WW * 3 * SS;

    __shared__ __align__(16) float qt[8][3][WW];     // 6 KB: per-row (q, sin, cos)
    __shared__ __align__(16) float ebuf[SS][8];      // 8 KB
    __shared__ __align__(16) float ypart[4][8][WW];  // 8 KB
    __shared__ float zs[4][8];

    const int tid = threadIdx.x, lane = tid & 63, wid = tid >> 6;

    // stage q triples (1536 contiguous floats)
    {
        const f32x4* qsrc = reinterpret_cast<const f32x4*>(QT + ((size_t)bh * SS + row0) * 3 * WW);
        f32x4* qdst = reinterpret_cast<f32x4*>(&qt[0][0][0]);
        qdst[tid] = qsrc[tid];
        if (tid < 128) qdst[tid + 256] = qsrc[tid + 256];
    }
    const float mt = -10000.0f * (1.0f - mask[b * SS + tid]);
    __syncthreads();

    float pg[8] = {1.f,1.f,1.f,1.f,1.f,1.f,1.f,1.f};
    for (int g = 0; g < 8; ++g) {                    // runtime loop (I$)
        const float* kg = kt + (size_t)g * 8 * 3 * SS + tid;
        float kk[8], sk[8], ck[8];
        #pragma unroll
        for (int j = 0; j < 8; ++j) {
            kk[j] = kg[j * 3 * SS];
            sk[j] = kg[j * 3 * SS + SS];
            ck[j] = kg[j * 3 * SS + 2 * SS];
        }
        #pragma unroll
        for (int r = 0; r < 8; ++r) {
            f32x4 q0 = *reinterpret_cast<const f32x4*>(&qt[r][0][g*8]);
            f32x4 q1 = *reinterpret_cast<const f32x4*>(&qt[r][0][g*8+4]);
            f32x4 s0 = *reinterpret_cast<const f32x4*>(&qt[r][1][g*8]);
            f32x4 s1 = *reinterpret_cast<const f32x4*>(&qt[r][1][g*8+4]);
            f32x4 c0 = *reinterpret_cast<const f32x4*>(&qt[r][2][g*8]);
            f32x4 c1 = *reinterpret_cast<const f32x4*>(&qt[r][2][g*8+4]);
            float ps = 1.f, pt = 1.f;
            #pragma unroll
            for (int j = 0; j < 8; ++j) {
                float qv = (j < 4) ? q0[j] : q1[j-4];
                float sq = (j < 4) ? s0[j] : s1[j-4];
                float cq = (j < 4) ? c0[j] : c1[j-4];
                float t  = qv - kk[j];
                float at = fmaxf(fabsf(t), EPS);
                float sn = fmaf(sq, ck[j], -(cq * sk[j]));   // sin(q^ - k^)
                sn = (fabsf(t) < EPS) ? at : sn;             // factor -> 1 near t=0
                ps *= sn;
                pt *= at;
            }
            pg[r] *= (ps * C8) * __builtin_amdgcn_rcpf(pt);
        }
    }

    // e = exp(score + maskterm), score = pg^4; stash + per-wave Z
    float e[8];
    #pragma unroll
    for (int r = 0; r < 8; ++r) {
        float p = pg[r];
        p *= p; p *= p;
        e[r] = __expf(p + mt);
    }
    {
        f32x4 e0, e1;
        #pragma unroll
        for (int r = 0; r < 4; ++r) { e0[r] = e[r]; e1[r] = e[r+4]; }
        *reinterpret_cast<f32x4*>(&ebuf[tid][0]) = e0;
        *reinterpret_cast<f32x4*>(&ebuf[tid][4]) = e1;
    }
    #pragma unroll
    for (int r = 0; r < 8; ++r) {
        float z = e[r];
        #pragma unroll
        for (int off = 32; off; off >>= 1) z += __shfl_xor(z, off);
        if (lane == 0) zs[wid][r] = z;
    }

    // PV: lane = output dim w; wave covers its own 64 keys
    float y[8] = {0.f,0.f,0.f,0.f,0.f,0.f,0.f,0.f};
    const float* vb = Vg + (size_t)(wid * 64) * WW + lane;
    #pragma unroll 16
    for (int ii = 0; ii < 64; ++ii) {
        float v = vb[ii * WW];
        f32x4 ea = *reinterpret_cast<const f32x4*>(&ebuf[wid*64 + ii][0]);
        f32x4 eb = *reinterpret_cast<const f32x4*>(&ebuf[wid*64 + ii][4]);
        y[0] = fmaf(ea[0], v, y[0]); y[1] = fmaf(ea[1], v, y[1]);
        y[2] = fmaf(ea[2], v, y[2]); y[3] = fmaf(ea[3], v, y[3]);
        y[4] = fmaf(eb[0], v, y[4]); y[5] = fmaf(eb[1], v, y[5]);
        y[6] = fmaf(eb[2], v, y[6]); y[7] = fmaf(eb[3], v, y[7]);
    }
    #pragma unroll
    for (int r = 0; r < 8; ++r) ypart[wid][r][lane] = y[r];
    __syncthreads();

    {
        const int r0 = tid >> 6;
        #pragma unroll
        for (int q = 0; q < 2; ++q) {
            int rr = r0 + q * 4;
            float yy = ypart[0][rr][lane] + ypart[1][rr][lane]
                     + ypart[2][rr][lane] + ypart[3][rr][lane];
            float zz = zs[0][rr] + zs[1][rr] + zs[2][rr] + zs[3][rr];
            out[((size_t)b * SS + row0 + rr) * DD + h * WW + lane] = yy * __builtin_amdgcn_rcpf(zz);
        }
    }
}

extern "C" void kernel_launch(void* const* d_in, const int* in_sizes, int n_in,
                              void* d_out, int out_size, void* d_ws, size_t ws_size,
                              hipStream_t stream) {
    const float* x    = (const float*)d_in[0];
    const float* mask = (const float*)d_in[1];
    const float* Wq   = (const float*)d_in[2];
    const float* bq   = (const float*)d_in[3];
    const float* Wk   = (const float*)d_in[4];
    const float* bk   = (const float*)d_in[5];
    const float* Wv   = (const float*)d_in[6];
    const float* bv   = (const float*)d_in[7];
    float* out = (float*)d_out;

    float*          qkv = (float*)d_ws;
    unsigned short* Ab  = (unsigned short*)((char*)d_ws + A_OFF_BYTES);
    unsigned short* Bb  = (unsigned short*)((char*)d_ws + B_OFF_BYTES);
    float*          QTp = (float*)((char*)d_ws + QT_OFF_BYTES);
    float*          KTp = (float*)((char*)d_ws + KT_OFF_BYTES);

    conv_all<<<dim3(XBLKS + WBLKS), 256, 0, stream>>>(x, Wq, Wk, Wv, Ab, Bb);
    gemm_qkv<<<dim3(512/64, 2304/64), 256, 0, stream>>>(Ab, Bb, bq, bk, bv, qkv);
    prep<<<dim3(4, NB*NH), 256, 0, stream>>>(qkv, QTp, KTp);
    fattn<<<dim3(SS/8, NB*NH), 256, 0, stream>>>(qkv, QTp, KTp, mask, out);
}

// Round 6
// 77.788 us; speedup vs baseline: 1.4597x; 1.4597x over previous
//
#include <hip/hip_runtime.h>
#include <math.h>

#define NB 2
#define SS 256
#define DD 768
#define NH 12
#define WW 64

using f32x4  = __attribute__((ext_vector_type(4))) float;
using bf16x8 = __attribute__((ext_vector_type(8))) short;

constexpr float R2  = 0.25f;           // R/2: revolutions pre-scale for v_sin/v_cos
constexpr float C8  = 4.1168160e-7f;   // (2*pi)^-8
constexpr float EPS = 1e-4f;

// ws layout (bytes):
//   qkv f32:  [0, 4718592)         3 * (2*12*256*64) * 4
//   A' bf16:  [4718592, 6291456)   512 x 1536  (xh | xl)
//   B' bf16:  [6291456, 13369344)  2304 x 1536 (Wh | Wl)
//   QT  f32:  [13369344, 18087936) [bh][row][3][64]  (q*R2, sin, cos)
//   KT  f32:  [18087936, 22806528) [bh][dim][3][256] (k*R2, sin, cos) key-coalesced
#define QKV_ELEMS (NB*NH*SS*WW)
#define A_OFF_BYTES  4718592u
#define B_OFF_BYTES  6291456u
#define QT_OFF_BYTES 13369344u
#define KT_OFF_BYTES 18087936u

#define XBLKS 384    // 512*768/4/256
#define WBLKS 1728   // 3*768*768/4/256

__device__ __forceinline__ unsigned short bf16_rn(float f) {
    unsigned u = __builtin_bit_cast(unsigned, f);
    u += 0x7fffu + ((u >> 16) & 1u);
    return (unsigned short)(u >> 16);
}

// ---------------- merged split conversions: x -> A' [xh|xl], W -> B' [Wh|Wl] ----------------
__global__ __launch_bounds__(256) void conv_all(
        const float* __restrict__ x,
        const float* __restrict__ Wq, const float* __restrict__ Wk, const float* __restrict__ Wv,
        unsigned short* __restrict__ A, unsigned short* __restrict__ B) {
    int bid = blockIdx.x;
    const float* src;
    unsigned short* dstrow;
    if (bid < XBLKS) {
        int idx = bid * 256 + threadIdx.x;
        int m = idx / (DD/4);
        int c = (idx - m*(DD/4)) * 4;
        src = x + (size_t)idx * 4;
        dstrow = A + (size_t)m * 1536 + c;
    } else {
        int idx = (bid - XBLKS) * 256 + threadIdx.x;
        int p = idx / (768*192);
        int rem = idx - p*(768*192);
        const float* W = (p == 0) ? Wq : (p == 1) ? Wk : Wv;
        int j = rem / 192;
        int c = (rem - j*192) * 4;
        src = W + (size_t)rem * 4;
        dstrow = B + (size_t)(p*768 + j) * 1536 + c;
    }
    float4 v = *reinterpret_cast<const float4*>(src);
    float vv[4] = {v.x, v.y, v.z, v.w};
    unsigned short h[4], l[4];
    #pragma unroll
    for (int e = 0; e < 4; ++e) {
        h[e] = bf16_rn(vv[e]);
        float hf = __builtin_bit_cast(float, (unsigned)h[e] << 16);
        l[e] = bf16_rn(vv[e] - hf);
    }
    *reinterpret_cast<ushort4*>(dstrow)       = make_ushort4(h[0], h[1], h[2], h[3]);
    *reinterpret_cast<ushort4*>(dstrow + 768) = make_ushort4(l[0], l[1], l[2], l[3]);
}

// ---------------- split-bf16 MFMA GEMM (R3 structure + prefetch pipeline) ----------------
// 32x32 tile, 4 waves split-K (wid*192 slice; 3 segs: xh*Wh, xh*Wl, xl*Wh), LDS reduce.
// grid (16, 72) = 1152 blocks. 1-deep register double-buffer on the 18-step K loop.
__global__ __launch_bounds__(256, 2) void gemm_qkv(
        const unsigned short* __restrict__ A, const unsigned short* __restrict__ B,
        const float* __restrict__ bq, const float* __restrict__ bk, const float* __restrict__ bv,
        float* __restrict__ qkv) {
    __shared__ float red[4][32*32];
    const int tid = threadIdx.x;
    const int wid = tid >> 6, l = tid & 63;
    const int lr = l & 15, lo_ = l >> 4;
    const int m0 = blockIdx.x * 32, n0 = blockIdx.y * 32;

    const unsigned short* Ap = A + (size_t)(m0 + lr) * 1536 + wid * 192 + lo_ * 8;
    const unsigned short* Bp = B + (size_t)(n0 + lr) * 1536 + wid * 192 + lo_ * 8;

    // per-step offsets: seg = it/6, kk = it%6; A gets +768 on seg2 (xl), B on seg1 (Wl)
    f32x4 acc00 = 0.f, acc01 = 0.f, acc10 = 0.f, acc11 = 0.f;

    bf16x8 ca0, ca1, cb0, cb1, na0, na1, nb0, nb1;
    ca0 = *reinterpret_cast<const bf16x8*>(Ap);
    ca1 = *reinterpret_cast<const bf16x8*>(Ap + 16*1536);
    cb0 = *reinterpret_cast<const bf16x8*>(Bp);
    cb1 = *reinterpret_cast<const bf16x8*>(Bp + 16*1536);

    #pragma unroll
    for (int it = 0; it < 18; ++it) {
        if (it < 17) {
            const int it1 = it + 1;
            const int seg1 = it1 / 6, kk1 = it1 - seg1 * 6;
            const int ao = ((seg1 == 2) ? 768 : 0) + kk1 * 32;
            const int bo = ((seg1 == 1) ? 768 : 0) + kk1 * 32;
            na0 = *reinterpret_cast<const bf16x8*>(Ap + ao);
            na1 = *reinterpret_cast<const bf16x8*>(Ap + 16*1536 + ao);
            nb0 = *reinterpret_cast<const bf16x8*>(Bp + bo);
            nb1 = *reinterpret_cast<const bf16x8*>(Bp + 16*1536 + bo);
        }
        acc00 = __builtin_amdgcn_mfma_f32_16x16x32_bf16(ca0, cb0, acc00, 0, 0, 0);
        acc01 = __builtin_amdgcn_mfma_f32_16x16x32_bf16(ca0, cb1, acc01, 0, 0, 0);
        acc10 = __builtin_amdgcn_mfma_f32_16x16x32_bf16(ca1, cb0, acc10, 0, 0, 0);
        acc11 = __builtin_amdgcn_mfma_f32_16x16x32_bf16(ca1, cb1, acc11, 0, 0, 0);
        ca0 = na0; ca1 = na1; cb0 = nb0; cb1 = nb1;
    }

    // D layout (m89-verified): col = lane&15, row = (lane>>4)*4 + reg
    #pragma unroll
    for (int j = 0; j < 4; ++j) {
        int r0 = lo_ * 4 + j;
        red[wid][(r0     ) * 32 + lr     ] = acc00[j];
        red[wid][(r0     ) * 32 + lr + 16] = acc01[j];
        red[wid][(r0 + 16) * 32 + lr     ] = acc10[j];
        red[wid][(r0 + 16) * 32 + lr + 16] = acc11[j];
    }
    __syncthreads();

    int row = tid >> 3, col = (tid & 7) * 4;
    f32x4 s = *reinterpret_cast<f32x4*>(&red[0][row*32 + col]);
    #pragma unroll
    for (int w = 1; w < 4; ++w)
        s += *reinterpret_cast<f32x4*>(&red[w][row*32 + col]);

    int n = n0 + col;
    int which = n / 768;
    int jj = n - which * 768;
    const float* bias = (which == 0) ? bq : (which == 1) ? bk : bv;
    float4 bb = *reinterpret_cast<const float4*>(&bias[jj]);
    s[0] += bb.x; s[1] += bb.y; s[2] += bb.z; s[3] += bb.w;

    int m = m0 + row, b_ = m >> 8, s_ = m & 255;
    int head = jj >> 6, w = jj & 63;
    float* o = qkv + (size_t)which * QKV_ELEMS + (((size_t)b_ * NH + head) * SS + s_) * WW + w;
    *reinterpret_cast<float4*>(o) = make_float4(s[0], s[1], s[2], s[3]);
}

// ---------------- prep: q,k -> (val*R2, sin, cos) triples ----------------
__global__ __launch_bounds__(256) void prep(const float* __restrict__ qkv,
                                            float* __restrict__ QT, float* __restrict__ KT) {
    const int c = blockIdx.x, bh = blockIdx.y;
    const int lane = threadIdx.x & 63, wv = threadIdx.x >> 6;
    const int key = c * 64 + lane;
    const int d0 = wv * 16;
    const float* q = qkv + ((size_t)bh * SS + key) * WW + d0;
    const float* k = qkv + QKV_ELEMS + ((size_t)bh * SS + key) * WW + d0;
    float* qt = QT + ((size_t)bh * SS + key) * 3 * WW;     // [key][3][64]
    float* kt = KT + (size_t)bh * WW * 3 * SS;             // [d][3][256]
    #pragma unroll
    for (int g = 0; g < 4; ++g) {
        float4 qv = *reinterpret_cast<const float4*>(q + g * 4);
        float4 kv = *reinterpret_cast<const float4*>(k + g * 4);
        float qa[4] = {qv.x, qv.y, qv.z, qv.w};
        float ka[4] = {kv.x, kv.y, kv.z, kv.w};
        f32x4 qr, qs, qc;
        #pragma unroll
        for (int e = 0; e < 4; ++e) {
            float a = R2 * qa[e];
            qr[e] = a;
            qs[e] = __builtin_amdgcn_sinf(a);
            qc[e] = __builtin_amdgcn_cosf(a);
        }
        *reinterpret_cast<f32x4*>(qt + 0 * WW + d0 + g * 4) = qr;
        *reinterpret_cast<f32x4*>(qt + 1 * WW + d0 + g * 4) = qs;
        *reinterpret_cast<f32x4*>(qt + 2 * WW + d0 + g * 4) = qc;
        #pragma unroll
        for (int e = 0; e < 4; ++e) {
            float a = R2 * ka[e];
            int d = d0 + g * 4 + e;
            kt[(d * 3 + 0) * SS + key] = a;
            kt[(d * 3 + 1) * SS + key] = __builtin_amdgcn_sinf(a);
            kt[(d * 3 + 2) * SS + key] = __builtin_amdgcn_cosf(a);
        }
    }
}

// ---------------- Fourier attention v5: transcendental-free inner loop ----------------
__global__ __launch_bounds__(256, 3) void fattn(
    const float* __restrict__ qkv, const float* __restrict__ QT, const float* __restrict__ KT,
    const float* __restrict__ mask, float* __restrict__ out)
{
    const int bh = blockIdx.y;
    const int b = bh / NH, h = bh - b * NH;
    const int row0 = blockIdx.x * 8;

    const float* Vg = qkv + (size_t)(2 * QKV_ELEMS) + (size_t)bh * SS * WW;
    const float* kt = KT + (size_t)bh * WW * 3 * SS;

    __shared__ __align__(16) float qt[8][3][WW];     // 6 KB: per-row (q, sin, cos)
    __shared__ __align__(16) float ebuf[SS][8];      // 8 KB
    __shared__ __align__(16) float ypart[4][8][WW];  // 8 KB
    __shared__ float zs[4][8];

    const int tid = threadIdx.x, lane = tid & 63, wid = tid >> 6;

    // stage q triples (1536 contiguous floats)
    {
        const f32x4* qsrc = reinterpret_cast<const f32x4*>(QT + ((size_t)bh * SS + row0) * 3 * WW);
        f32x4* qdst = reinterpret_cast<f32x4*>(&qt[0][0][0]);
        qdst[tid] = qsrc[tid];
        if (tid < 128) qdst[tid + 256] = qsrc[tid + 256];
    }
    const float mt = -10000.0f * (1.0f - mask[b * SS + tid]);
    __syncthreads();

    float pg[8] = {1.f,1.f,1.f,1.f,1.f,1.f,1.f,1.f};
    for (int g = 0; g < 8; ++g) {                    // runtime loop (I$)
        const float* kg = kt + (size_t)g * 8 * 3 * SS + tid;
        float kk[8], sk[8], ck[8];
        #pragma unroll
        for (int j = 0; j < 8; ++j) {
            kk[j] = kg[j * 3 * SS];
            sk[j] = kg[j * 3 * SS + SS];
            ck[j] = kg[j * 3 * SS + 2 * SS];
        }
        #pragma unroll
        for (int r = 0; r < 8; ++r) {
            f32x4 q0 = *reinterpret_cast<const f32x4*>(&qt[r][0][g*8]);
            f32x4 q1 = *reinterpret_cast<const f32x4*>(&qt[r][0][g*8+4]);
            f32x4 s0 = *reinterpret_cast<const f32x4*>(&qt[r][1][g*8]);
            f32x4 s1 = *reinterpret_cast<const f32x4*>(&qt[r][1][g*8+4]);
            f32x4 c0 = *reinterpret_cast<const f32x4*>(&qt[r][2][g*8]);
            f32x4 c1 = *reinterpret_cast<const f32x4*>(&qt[r][2][g*8+4]);
            float ps = 1.f, pt = 1.f;
            #pragma unroll
            for (int j = 0; j < 8; ++j) {
                float qv = (j < 4) ? q0[j] : q1[j-4];
                float sq = (j < 4) ? s0[j] : s1[j-4];
                float cq = (j < 4) ? c0[j] : c1[j-4];
                float t  = qv - kk[j];
                float at = fmaxf(fabsf(t), EPS);
                float sn = fmaf(sq, ck[j], -(cq * sk[j]));   // sin(q^ - k^)
                sn = (fabsf(t) < EPS) ? at : sn;             // factor -> 1 near t=0
                ps *= sn;
                pt *= at;
            }
            pg[r] *= (ps * C8) * __builtin_amdgcn_rcpf(pt);
        }
    }

    // e = exp(score + maskterm), score = pg^4; stash + per-wave Z
    float e[8];
    #pragma unroll
    for (int r = 0; r < 8; ++r) {
        float p = pg[r];
        p *= p; p *= p;
        e[r] = __expf(p + mt);
    }
    {
        f32x4 e0, e1;
        #pragma unroll
        for (int r = 0; r < 4; ++r) { e0[r] = e[r]; e1[r] = e[r+4]; }
        *reinterpret_cast<f32x4*>(&ebuf[tid][0]) = e0;
        *reinterpret_cast<f32x4*>(&ebuf[tid][4]) = e1;
    }
    #pragma unroll
    for (int r = 0; r < 8; ++r) {
        float z = e[r];
        #pragma unroll
        for (int off = 32; off; off >>= 1) z += __shfl_xor(z, off);
        if (lane == 0) zs[wid][r] = z;
    }

    // PV: lane = output dim w; wave covers its own 64 keys
    float y[8] = {0.f,0.f,0.f,0.f,0.f,0.f,0.f,0.f};
    const float* vb = Vg + (size_t)(wid * 64) * WW + lane;
    #pragma unroll 16
    for (int ii = 0; ii < 64; ++ii) {
        float v = vb[ii * WW];
        f32x4 ea = *reinterpret_cast<const f32x4*>(&ebuf[wid*64 + ii][0]);
        f32x4 eb = *reinterpret_cast<const f32x4*>(&ebuf[wid*64 + ii][4]);
        y[0] = fmaf(ea[0], v, y[0]); y[1] = fmaf(ea[1], v, y[1]);
        y[2] = fmaf(ea[2], v, y[2]); y[3] = fmaf(ea[3], v, y[3]);
        y[4] = fmaf(eb[0], v, y[4]); y[5] = fmaf(eb[1], v, y[5]);
        y[6] = fmaf(eb[2], v, y[6]); y[7] = fmaf(eb[3], v, y[7]);
    }
    #pragma unroll
    for (int r = 0; r < 8; ++r) ypart[wid][r][lane] = y[r];
    __syncthreads();

    {
        const int r0 = tid >> 6;
        #pragma unroll
        for (int q = 0; q < 2; ++q) {
            int rr = r0 + q * 4;
            float yy = ypart[0][rr][lane] + ypart[1][rr][lane]
                     + ypart[2][rr][lane] + ypart[3][rr][lane];
            float zz = zs[0][rr] + zs[1][rr] + zs[2][rr] + zs[3][rr];
            out[((size_t)b * SS + row0 + rr) * DD + h * WW + lane] = yy * __builtin_amdgcn_rcpf(zz);
        }
    }
}

extern "C" void kernel_launch(void* const* d_in, const int* in_sizes, int n_in,
                              void* d_out, int out_size, void* d_ws, size_t ws_size,
                              hipStream_t stream) {
    const float* x    = (const float*)d_in[0];
    const float* mask = (const float*)d_in[1];
    const float* Wq   = (const float*)d_in[2];
    const float* bq   = (const float*)d_in[3];
    const float* Wk   = (const float*)d_in[4];
    const float* bk   = (const float*)d_in[5];
    const float* Wv   = (const float*)d_in[6];
    const float* bv   = (const float*)d_in[7];
    float* out = (float*)d_out;

    float*          qkv = (float*)d_ws;
    unsigned short* Ab  = (unsigned short*)((char*)d_ws + A_OFF_BYTES);
    unsigned short* Bb  = (unsigned short*)((char*)d_ws + B_OFF_BYTES);
    float*          QTp = (float*)((char*)d_ws + QT_OFF_BYTES);
    float*          KTp = (float*)((char*)d_ws + KT_OFF_BYTES);

    conv_all<<<dim3(XBLKS + WBLKS), 256, 0, stream>>>(x, Wq, Wk, Wv, Ab, Bb);
    gemm_qkv<<<dim3(512/32, 2304/32), 256, 0, stream>>>(Ab, Bb, bq, bk, bv, qkv);
    prep<<<dim3(4, NB*NH), 256, 0, stream>>>(qkv, QTp, KTp);
    fattn<<<dim3(SS/8, NB*NH), 256, 0, stream>>>(qkv, QTp, KTp, mask, out);
}